// Round 2
// baseline (5978.243 us; speedup 1.0000x reference)
//
#include <hip/hip_runtime.h>

// GCNEncoder — correctness-bisection round: brute-force components, semantics
// 1:1 with the reference. out = A_hat( relu( BN( A_hat(x W1^T) ) ) ) W2^T + b2
//   A_hat = D^-1/2 (A + I) D^-1/2, deg at destination incl self-loop.
// b1 cancels exactly through BatchNorm (constant per-feature shift) -> skipped.

// ---------- dtype probe: edge_index may be int64 or int32 ----------
__global__ void k_detect(const int* __restrict__ ei32, int* __restrict__ flag) {
    if (threadIdx.x == 0 && blockIdx.x == 0) {
        int o = 0;
        for (int q = 0; q < 16; ++q) o |= ei32[2 * q + 1];
        flag[0] = (o == 0) ? 1 : 0;  // 1 => int64 (high dwords all zero)
    }
}

// ---------- degree count (real edges at dst) ----------
__global__ __launch_bounds__(256) void k_count(const void* __restrict__ eiv,
                                               int* __restrict__ cnt,
                                               const int* __restrict__ flag,
                                               int E, int N) {
    int e = blockIdx.x * 256 + threadIdx.x;
    if (e >= E) return;
    int d;
    if (flag[0]) d = (int)((const long long*)eiv)[E + e];
    else         d = ((const int*)eiv)[E + e];
    if ((unsigned)d < (unsigned)N) atomicAdd(&cnt[d], 1);
}

// ---------- dis = rsqrt(deg+1) ----------
__global__ __launch_bounds__(256) void k_dis(const int* __restrict__ cnt,
                                             float* __restrict__ dis, int N) {
    int i = blockIdx.x * 256 + threadIdx.x;
    if (i < N) dis[i] = rsqrtf((float)cnt[i] + 1.0f);
}

// ---------- GEMM1 (naive, 1 thread per output): h1[n][o] = x[n]·W1[o] ----------
__global__ __launch_bounds__(256) void k_gemm1(const float* __restrict__ x,
                                               const float* __restrict__ W1,
                                               float* __restrict__ h1, int NF) {
    int idx = blockIdx.x * 256 + threadIdx.x;
    if (idx >= NF) return;
    int n = idx >> 7, o = idx & 127;
    const float4* xr = (const float4*)x + n * 32;
    const float4* wr = (const float4*)W1 + o * 32;
    float acc = 0.f;
    for (int q = 0; q < 32; ++q) {
        float4 a = xr[q], b = wr[q];
        acc += a.x * b.x + a.y * b.y + a.z * b.z + a.w * b.w;
    }
    h1[idx] = acc;
}

// ---------- edge scatter layer 1: agg1[d] += dis[s]*dis[d]*h1[s] ----------
__global__ __launch_bounds__(256) void k_scatter1(const void* __restrict__ eiv,
                                                  const float* __restrict__ h1,
                                                  const float* __restrict__ dis,
                                                  float* __restrict__ agg1,
                                                  const int* __restrict__ flag,
                                                  int E, int N) {
    int idx = blockIdx.x * 256 + threadIdx.x;   // e * 32 + q
    if (idx >= E * 32) return;
    int e = idx >> 5, q = idx & 31;
    int s, d;
    if (flag[0]) {
        s = (int)((const long long*)eiv)[e];
        d = (int)((const long long*)eiv)[E + e];
    } else {
        s = ((const int*)eiv)[e];
        d = ((const int*)eiv)[E + e];
    }
    if ((unsigned)s >= (unsigned)N || (unsigned)d >= (unsigned)N) return;
    float w = dis[s] * dis[d];
    float4 v = ((const float4*)h1)[s * 32 + q];
    float* p = &agg1[d * 128 + q * 4];
    atomicAdd(p + 0, w * v.x);
    atomicAdd(p + 1, w * v.y);
    atomicAdd(p + 2, w * v.z);
    atomicAdd(p + 3, w * v.w);
}

// ---------- self-loop layer 1: agg1[i] += dis[i]^2 * h1[i] ----------
__global__ __launch_bounds__(256) void k_self1(const float* __restrict__ h1,
                                               const float* __restrict__ dis,
                                               float* __restrict__ agg1, int NF) {
    int idx = blockIdx.x * 256 + threadIdx.x;
    if (idx >= NF) return;
    int i = idx >> 7;
    float di = dis[i];
    agg1[idx] += di * di * h1[idx];
}

// ---------- BN stats: per-feature sum & sumsq over nodes ----------
__global__ __launch_bounds__(256) void k_bnstats(const float* __restrict__ agg1,
                                                 float* __restrict__ stats, int N) {
    int t = threadIdx.x;
    int f = t & 127, half = t >> 7;
    float s = 0.f, sq = 0.f;
    int stride = gridDim.x * 2;
    for (int r = blockIdx.x * 2 + half; r < N; r += stride) {
        float v = agg1[r * 128 + f];
        s += v; sq += v * v;
    }
    __shared__ float ls[256], lq[256];
    ls[t] = s; lq[t] = sq;
    __syncthreads();
    if (t < 128) {
        atomicAdd(&stats[f], ls[t] + ls[t + 128]);
        atomicAdd(&stats[128 + f], lq[t] + lq[t + 128]);
    }
}

// ---------- BN finalize: scale/shift ----------
__global__ void k_bnfin(float* __restrict__ stats, const float* __restrict__ gamma,
                        const float* __restrict__ beta, int N) {
    int f = threadIdx.x;
    if (f >= 128) return;
    float invN = 1.0f / (float)N;
    float mean = stats[f] * invN;
    float var = stats[128 + f] * invN - mean * mean;
    var = fmaxf(var, 0.f);
    float inv = rsqrtf(var + 1e-5f);
    float sc = gamma[f] * inv;
    stats[256 + f] = sc;
    stats[384 + f] = beta[f] - mean * sc;
}

// ---------- GEMM2 (naive): h2[n][o] = sum_k relu(agg1[n][k]*sc+sh) * W2[o][k] ----------
__global__ __launch_bounds__(256) void k_gemm2(const float* __restrict__ agg1,
                                               const float* __restrict__ W2,
                                               const float* __restrict__ stats,
                                               float* __restrict__ h2, int NO) {
    int idx = blockIdx.x * 256 + threadIdx.x;
    if (idx >= NO) return;
    int n = idx >> 6, o = idx & 63;
    const float4* ar = (const float4*)agg1 + n * 32;
    const float4* wr = (const float4*)W2 + o * 32;
    const float4* st = (const float4*)stats;
    float acc = 0.f;
    for (int q = 0; q < 32; ++q) {
        float4 a = ar[q], b = wr[q], sc = st[64 + q], sh = st[96 + q];
        float r0 = fmaxf(a.x * sc.x + sh.x, 0.f);
        float r1 = fmaxf(a.y * sc.y + sh.y, 0.f);
        float r2 = fmaxf(a.z * sc.z + sh.z, 0.f);
        float r3 = fmaxf(a.w * sc.w + sh.w, 0.f);
        acc += r0 * b.x + r1 * b.y + r2 * b.z + r3 * b.w;
    }
    h2[idx] = acc;
}

// ---------- out init: self-loop + bias ----------
__global__ __launch_bounds__(256) void k_initout(const float* __restrict__ h2,
                                                 const float* __restrict__ dis,
                                                 const float* __restrict__ b2,
                                                 float* __restrict__ out, int NO) {
    int idx = blockIdx.x * 256 + threadIdx.x;
    if (idx >= NO) return;
    int i = idx >> 6, f = idx & 63;
    float di = dis[i];
    out[idx] = di * di * h2[idx] + b2[f];
}

// ---------- edge scatter layer 2: out[d] += dis[s]*dis[d]*h2[s] ----------
__global__ __launch_bounds__(256) void k_scatter2(const void* __restrict__ eiv,
                                                  const float* __restrict__ h2,
                                                  const float* __restrict__ dis,
                                                  float* __restrict__ out,
                                                  const int* __restrict__ flag,
                                                  int E, int N) {
    int idx = blockIdx.x * 256 + threadIdx.x;   // e * 16 + q
    if (idx >= E * 16) return;
    int e = idx >> 4, q = idx & 15;
    int s, d;
    if (flag[0]) {
        s = (int)((const long long*)eiv)[e];
        d = (int)((const long long*)eiv)[E + e];
    } else {
        s = ((const int*)eiv)[e];
        d = ((const int*)eiv)[E + e];
    }
    if ((unsigned)s >= (unsigned)N || (unsigned)d >= (unsigned)N) return;
    float w = dis[s] * dis[d];
    float4 v = ((const float4*)h2)[s * 16 + q];
    float* p = &out[d * 64 + q * 4];
    atomicAdd(p + 0, w * v.x);
    atomicAdd(p + 1, w * v.y);
    atomicAdd(p + 2, w * v.z);
    atomicAdd(p + 3, w * v.w);
}

extern "C" void kernel_launch(void* const* d_in, const int* in_sizes, int n_in,
                              void* d_out, int out_size, void* d_ws, size_t ws_size,
                              hipStream_t stream) {
    const float* x     = (const float*)d_in[0];
    const void*  ei    = d_in[1];            // int64 or int32, probed on device
    const float* W1    = (const float*)d_in[2];
    // d_in[3] = b1: cancels exactly through BatchNorm -> skipped (also zeros)
    const float* gamma = (const float*)d_in[4];
    const float* beta  = (const float*)d_in[5];
    const float* W2    = (const float*)d_in[6];
    const float* b2    = (const float*)d_in[7];
    float* out = (float*)d_out;

    int N = in_sizes[0] / 128;
    int E = in_sizes[1] / 2;
    int NF = N * 128;   // 12.8M
    int NO = N * 64;    // 6.4M

    // ---- workspace layout (all counts in elements) ----
    int*   cnt   = (int*)d_ws;                  // N
    int*   flag  = cnt + N;                     // 4
    float* stats = (float*)(flag + 4);          // 512: sum|sumsq|scale|shift
    float* dis   = stats + 512;                 // N
    float* h1    = dis + N;                     // N*128 (float4-aligned: N even)
    float* agg1  = h1 + (size_t)NF;             // N*128
    float* h2    = h1;                          // overlay: h1 dead after k_self1

    hipMemsetAsync(cnt, 0, (size_t)N * sizeof(int), stream);
    hipMemsetAsync(flag, 0, (4 + 512) * sizeof(int), stream);
    hipMemsetAsync(agg1, 0, (size_t)NF * sizeof(float), stream);

    k_detect<<<1, 64, 0, stream>>>((const int*)ei, flag);

    int gE   = (E + 255) / 256;
    int gN   = (N + 255) / 256;
    int gNF  = (NF + 255) / 256;
    int gNO  = (NO + 255) / 256;
    int gS1  = (E * 32 + 255) / 256;
    int gS2  = (E * 16 + 255) / 256;

    k_count<<<gE, 256, 0, stream>>>(ei, cnt, flag, E, N);
    k_dis<<<gN, 256, 0, stream>>>(cnt, dis, N);
    k_gemm1<<<gNF, 256, 0, stream>>>(x, W1, h1, NF);
    k_scatter1<<<gS1, 256, 0, stream>>>(ei, h1, dis, agg1, flag, E, N);
    k_self1<<<gNF, 256, 0, stream>>>(h1, dis, agg1, NF);
    k_bnstats<<<500, 256, 0, stream>>>(agg1, stats, N);
    k_bnfin<<<1, 128, 0, stream>>>(stats, gamma, beta, N);
    k_gemm2<<<gNO, 256, 0, stream>>>(agg1, W2, stats, h2, NO);
    k_initout<<<gNO, 256, 0, stream>>>(h2, dis, b2, out, NO);
    k_scatter2<<<gS2, 256, 0, stream>>>(ei, h2, dis, out, flag, E, N);
}

// Round 4
// 3229.465 us; speedup vs baseline: 1.8512x; 1.8512x over previous
//
#include <hip/hip_runtime.h>

// GCNEncoder — bisection round: round-2 passing kernel + ONE change:
// layer-1 aggregation via CSR (dst->src) + wave-per-node gather instead of
// per-edge atomics. Layer 2 still atomic scatter (round-2 verbatim).
// b1 cancels exactly through BatchNorm -> skipped.

// ---------- dtype probe: edge_index may be int64 or int32 ----------
__global__ void k_detect(const int* __restrict__ ei32, int* __restrict__ flag) {
    if (threadIdx.x == 0 && blockIdx.x == 0) {
        int o = 0;
        for (int q = 0; q < 16; ++q) o |= ei32[2 * q + 1];
        flag[0] = (o == 0) ? 1 : 0;  // 1 => int64 (high dwords all zero)
    }
}

// ---------- degree count (real edges at dst) ----------
__global__ __launch_bounds__(256) void k_count(const void* __restrict__ eiv,
                                               int* __restrict__ cnt,
                                               const int* __restrict__ flag,
                                               int E, int N) {
    int e = blockIdx.x * 256 + threadIdx.x;
    if (e >= E) return;
    int d;
    if (flag[0]) d = (int)((const long long*)eiv)[E + e];
    else         d = ((const int*)eiv)[E + e];
    if ((unsigned)d < (unsigned)N) atomicAdd(&cnt[d], 1);
}

// ---------- dis = rsqrt(deg+1); CSR region alloc via plain atomicAdd ----------
__global__ __launch_bounds__(256) void k_disalloc(const int* __restrict__ cnt,
                                                  float* __restrict__ dis,
                                                  int* __restrict__ rowptr,
                                                  int* __restrict__ rowcur,
                                                  int* __restrict__ total, int N) {
    int i = blockIdx.x * 256 + threadIdx.x;
    if (i >= N) return;
    int c = cnt[i];
    dis[i] = rsqrtf((float)c + 1.0f);
    int pos = atomicAdd(total, c);   // region order arbitrary; that's fine
    rowptr[i] = pos;
    rowcur[i] = pos;
}

// ---------- CSR fill ----------
__global__ __launch_bounds__(256) void k_fill(const void* __restrict__ eiv,
                                              int* __restrict__ rowcur,
                                              int* __restrict__ elist,
                                              const int* __restrict__ flag,
                                              int E, int N) {
    int e = blockIdx.x * 256 + threadIdx.x;
    if (e >= E) return;
    int s, d;
    if (flag[0]) {
        s = (int)((const long long*)eiv)[e];
        d = (int)((const long long*)eiv)[E + e];
    } else {
        s = ((const int*)eiv)[e];
        d = ((const int*)eiv)[E + e];
    }
    if ((unsigned)s >= (unsigned)N || (unsigned)d >= (unsigned)N) return;
    int p = atomicAdd(&rowcur[d], 1);
    elist[p] = s;
}

// ---------- GEMM1 (naive, round-2 verbatim): h1[n][o] = x[n]·W1[o] ----------
__global__ __launch_bounds__(256) void k_gemm1(const float* __restrict__ x,
                                               const float* __restrict__ W1,
                                               float* __restrict__ h1, int NF) {
    int idx = blockIdx.x * 256 + threadIdx.x;
    if (idx >= NF) return;
    int n = idx >> 7, o = idx & 127;
    const float4* xr = (const float4*)x + n * 32;
    const float4* wr = (const float4*)W1 + o * 32;
    float acc = 0.f;
    for (int q = 0; q < 32; ++q) {
        float4 a = xr[q], b = wr[q];
        acc += a.x * b.x + a.y * b.y + a.z * b.z + a.w * b.w;
    }
    h1[idx] = acc;
}

// ---------- NEW: layer-1 gather. One wave per node, lane = 2 feats.
// agg1[i] = dis_i*(sum_s dis_s*h1[s]) + dis_i^2*h1[i]   (self fused)
// elist/dis reads are wave-uniform (broadcast); h1 row gather is coalesced.
__global__ __launch_bounds__(256) void k_agg1(const float* __restrict__ h1,
                                              const float* __restrict__ dis,
                                              const int* __restrict__ rowptr,
                                              const int* __restrict__ cnt,
                                              const int* __restrict__ elist,
                                              float* __restrict__ agg1, int N) {
    int lane = threadIdx.x & 63;
    int i = blockIdx.x * 4 + (threadIdx.x >> 6);
    if (i >= N) return;
    const float2* h = (const float2*)h1;
    float accx = 0.f, accy = 0.f;
    int base = rowptr[i], c = cnt[i];
    for (int j = 0; j < c; ++j) {
        int s = elist[base + j];      // wave-uniform broadcast load
        float w = dis[s];             // wave-uniform broadcast load
        float2 v = h[s * 64 + lane];  // coalesced 512B row gather
        accx += w * v.x;
        accy += w * v.y;
    }
    float di = dis[i];
    float2 self = h[i * 64 + lane];
    float2 r;
    r.x = di * accx + di * di * self.x;
    r.y = di * accy + di * di * self.y;
    ((float2*)agg1)[i * 64 + lane] = r;
}

// ---------- BN stats (round-2 verbatim) ----------
__global__ __launch_bounds__(256) void k_bnstats(const float* __restrict__ agg1,
                                                 float* __restrict__ stats, int N) {
    int t = threadIdx.x;
    int f = t & 127, half = t >> 7;
    float s = 0.f, sq = 0.f;
    int stride = gridDim.x * 2;
    for (int r = blockIdx.x * 2 + half; r < N; r += stride) {
        float v = agg1[r * 128 + f];
        s += v; sq += v * v;
    }
    __shared__ float ls[256], lq[256];
    ls[t] = s; lq[t] = sq;
    __syncthreads();
    if (t < 128) {
        atomicAdd(&stats[f], ls[t] + ls[t + 128]);
        atomicAdd(&stats[128 + f], lq[t] + lq[t + 128]);
    }
}

// ---------- BN finalize (round-2 verbatim) ----------
__global__ void k_bnfin(float* __restrict__ stats, const float* __restrict__ gamma,
                        const float* __restrict__ beta, int N) {
    int f = threadIdx.x;
    if (f >= 128) return;
    float invN = 1.0f / (float)N;
    float mean = stats[f] * invN;
    float var = stats[128 + f] * invN - mean * mean;
    var = fmaxf(var, 0.f);
    float inv = rsqrtf(var + 1e-5f);
    float sc = gamma[f] * inv;
    stats[256 + f] = sc;
    stats[384 + f] = beta[f] - mean * sc;
}

// ---------- GEMM2 (naive, round-2 verbatim) ----------
__global__ __launch_bounds__(256) void k_gemm2(const float* __restrict__ agg1,
                                               const float* __restrict__ W2,
                                               const float* __restrict__ stats,
                                               float* __restrict__ h2, int NO) {
    int idx = blockIdx.x * 256 + threadIdx.x;
    if (idx >= NO) return;
    int n = idx >> 6, o = idx & 63;
    const float4* ar = (const float4*)agg1 + n * 32;
    const float4* wr = (const float4*)W2 + o * 32;
    const float4* st = (const float4*)stats;
    float acc = 0.f;
    for (int q = 0; q < 32; ++q) {
        float4 a = ar[q], b = wr[q], sc = st[64 + q], sh = st[96 + q];
        float r0 = fmaxf(a.x * sc.x + sh.x, 0.f);
        float r1 = fmaxf(a.y * sc.y + sh.y, 0.f);
        float r2 = fmaxf(a.z * sc.z + sh.z, 0.f);
        float r3 = fmaxf(a.w * sc.w + sh.w, 0.f);
        acc += r0 * b.x + r1 * b.y + r2 * b.z + r3 * b.w;
    }
    h2[idx] = acc;
}

// ---------- out init: self-loop + bias (round-2 verbatim) ----------
__global__ __launch_bounds__(256) void k_initout(const float* __restrict__ h2,
                                                 const float* __restrict__ dis,
                                                 const float* __restrict__ b2,
                                                 float* __restrict__ out, int NO) {
    int idx = blockIdx.x * 256 + threadIdx.x;
    if (idx >= NO) return;
    int i = idx >> 6, f = idx & 63;
    float di = dis[i];
    out[idx] = di * di * h2[idx] + b2[f];
}

// ---------- layer-2 atomic scatter (round-2 verbatim) ----------
__global__ __launch_bounds__(256) void k_scatter2(const void* __restrict__ eiv,
                                                  const float* __restrict__ h2,
                                                  const float* __restrict__ dis,
                                                  float* __restrict__ out,
                                                  const int* __restrict__ flag,
                                                  int E, int N) {
    int idx = blockIdx.x * 256 + threadIdx.x;   // e * 16 + q
    if (idx >= E * 16) return;
    int e = idx >> 4, q = idx & 15;
    int s, d;
    if (flag[0]) {
        s = (int)((const long long*)eiv)[e];
        d = (int)((const long long*)eiv)[E + e];
    } else {
        s = ((const int*)eiv)[e];
        d = ((const int*)eiv)[E + e];
    }
    if ((unsigned)s >= (unsigned)N || (unsigned)d >= (unsigned)N) return;
    float w = dis[s] * dis[d];
    float4 v = ((const float4*)h2)[s * 16 + q];
    float* p = &out[d * 64 + q * 4];
    atomicAdd(p + 0, w * v.x);
    atomicAdd(p + 1, w * v.y);
    atomicAdd(p + 2, w * v.z);
    atomicAdd(p + 3, w * v.w);
}

extern "C" void kernel_launch(void* const* d_in, const int* in_sizes, int n_in,
                              void* d_out, int out_size, void* d_ws, size_t ws_size,
                              hipStream_t stream) {
    const float* x     = (const float*)d_in[0];
    const void*  ei    = d_in[1];            // int64 or int32, probed on device
    const float* W1    = (const float*)d_in[2];
    // d_in[3] = b1: cancels exactly through BatchNorm -> skipped
    const float* gamma = (const float*)d_in[4];
    const float* beta  = (const float*)d_in[5];
    const float* W2    = (const float*)d_in[6];
    const float* b2    = (const float*)d_in[7];
    float* out = (float*)d_out;

    int N = in_sizes[0] / 128;
    int E = in_sizes[1] / 2;
    int NF = N * 128;
    int NO = N * 64;

    // ---- workspace layout (ints): ~110.4 MB peak (round-1 layout ran OK) ----
    int*   cnt    = (int*)d_ws;                          // N
    int*   rowptr = cnt + N;                             // N
    int*   rowcur = rowptr + N;                          // N
    int*   total4 = rowcur + N;                          // 4: [0]=alloc, [1]=flag
    float* stats  = (float*)(total4 + 4);                // 512
    float* dis    = stats + 512;                         // N
    int*   elist  = (int*)(dis + N);                     // E
    float* h1     = (float*)(elist + E);                 // N*128 f32 (16B-aligned)
    float* agg1   = h1 + (size_t)NF;                     // N*128 f32
    float* h2     = h1;                                  // overlay: h1 dead after agg1

    hipMemsetAsync(cnt, 0, (size_t)N * sizeof(int), stream);
    hipMemsetAsync(total4, 0, (4 + 512) * sizeof(int), stream);

    int* flag = total4 + 1;
    k_detect<<<1, 64, 0, stream>>>((const int*)ei, flag);

    int gE   = (E + 255) / 256;
    int gN   = (N + 255) / 256;
    int gNF  = (NF + 255) / 256;
    int gNO  = (NO + 255) / 256;
    int gAgg = (N + 3) / 4;
    int gS2  = (E * 16 + 255) / 256;

    k_count<<<gE, 256, 0, stream>>>(ei, cnt, flag, E, N);
    k_disalloc<<<gN, 256, 0, stream>>>(cnt, dis, rowptr, rowcur, total4, N);
    k_fill<<<gE, 256, 0, stream>>>(ei, rowcur, elist, flag, E, N);
    k_gemm1<<<gNF, 256, 0, stream>>>(x, W1, h1, NF);
    k_agg1<<<gAgg, 256, 0, stream>>>(h1, dis, rowptr, cnt, elist, agg1, N);
    k_bnstats<<<500, 256, 0, stream>>>(agg1, stats, N);
    k_bnfin<<<1, 128, 0, stream>>>(stats, gamma, beta, N);
    k_gemm2<<<gNO, 256, 0, stream>>>(agg1, W2, stats, h2, NO);
    k_initout<<<gNO, 256, 0, stream>>>(h2, dis, b2, out, NO);
    k_scatter2<<<gS2, 256, 0, stream>>>(ei, h2, dis, out, flag, E, N);
}

// Round 6
// 1819.391 us; speedup vs baseline: 3.2858x; 1.7750x over previous
//
#include <hip/hip_runtime.h>

// GCNEncoder — round 6: all-proven structures.
//   GEMM1/GEMM2: naive-proven structure widened to 4 outputs/thread (float4).
//   Aggregations: CSR + wave-per-node gather (proven R4) for both layers.
//   Tiled-LDS GEMM structure from R1 abandoned (convicted: failing R1/R3/R5).
// b1 cancels exactly through BatchNorm -> skipped.

// ---------- dtype probe: edge_index may be int64 or int32 ----------
__global__ void k_detect(const int* __restrict__ ei32, int* __restrict__ flag) {
    if (threadIdx.x == 0 && blockIdx.x == 0) {
        int o = 0;
        for (int q = 0; q < 16; ++q) o |= ei32[2 * q + 1];
        flag[0] = (o == 0) ? 1 : 0;  // 1 => int64 (high dwords all zero)
    }
}

// ---------- degree count (real edges at dst) ----------
__global__ __launch_bounds__(256) void k_count(const void* __restrict__ eiv,
                                               int* __restrict__ cnt,
                                               const int* __restrict__ flag,
                                               int E, int N) {
    int e = blockIdx.x * 256 + threadIdx.x;
    if (e >= E) return;
    int d;
    if (flag[0]) d = (int)((const long long*)eiv)[E + e];
    else         d = ((const int*)eiv)[E + e];
    if ((unsigned)d < (unsigned)N) atomicAdd(&cnt[d], 1);
}

// ---------- dis = rsqrt(deg+1); CSR region alloc via plain atomicAdd ----------
__global__ __launch_bounds__(256) void k_disalloc(const int* __restrict__ cnt,
                                                  float* __restrict__ dis,
                                                  int* __restrict__ rowptr,
                                                  int* __restrict__ rowcur,
                                                  int* __restrict__ total, int N) {
    int i = blockIdx.x * 256 + threadIdx.x;
    if (i >= N) return;
    int c = cnt[i];
    dis[i] = rsqrtf((float)c + 1.0f);
    int pos = atomicAdd(total, c);   // region order arbitrary; that's fine
    rowptr[i] = pos;
    rowcur[i] = pos;
}

// ---------- CSR fill ----------
__global__ __launch_bounds__(256) void k_fill(const void* __restrict__ eiv,
                                              int* __restrict__ rowcur,
                                              int* __restrict__ elist,
                                              const int* __restrict__ flag,
                                              int E, int N) {
    int e = blockIdx.x * 256 + threadIdx.x;
    if (e >= E) return;
    int s, d;
    if (flag[0]) {
        s = (int)((const long long*)eiv)[e];
        d = (int)((const long long*)eiv)[E + e];
    } else {
        s = ((const int*)eiv)[e];
        d = ((const int*)eiv)[E + e];
    }
    if ((unsigned)s >= (unsigned)N || (unsigned)d >= (unsigned)N) return;
    int p = atomicAdd(&rowcur[d], 1);
    elist[p] = s;
}

// ---------- GEMM1: proven naive structure, 4 outputs/thread ----------
// thread (n, q): h1[n][4q..4q+3] = x[n]·{W1 rows 4q..4q+3}
__global__ __launch_bounds__(256) void k_gemm1(const float* __restrict__ x,
                                               const float* __restrict__ W1,
                                               float* __restrict__ h1, int NT) {
    int idx = blockIdx.x * 256 + threadIdx.x;
    if (idx >= NT) return;                 // NT = N*32
    int n = idx >> 5, q = idx & 31;
    const float4* xr = (const float4*)x + n * 32;
    const float4* w0 = (const float4*)W1 + (q * 4) * 32;  // rows 4q..4q+3
    float4 acc = make_float4(0.f, 0.f, 0.f, 0.f);
    for (int k = 0; k < 32; ++k) {
        float4 a = xr[k];
        float4 b0 = w0[k], b1 = w0[32 + k], b2 = w0[64 + k], b3 = w0[96 + k];
        acc.x += a.x * b0.x + a.y * b0.y + a.z * b0.z + a.w * b0.w;
        acc.y += a.x * b1.x + a.y * b1.y + a.z * b1.z + a.w * b1.w;
        acc.z += a.x * b2.x + a.y * b2.y + a.z * b2.z + a.w * b2.w;
        acc.w += a.x * b3.x + a.y * b3.y + a.z * b3.z + a.w * b3.w;
    }
    ((float4*)h1)[idx] = acc;
}

// ---------- layer-1 gather (round-4 verbatim, proven) ----------
__global__ __launch_bounds__(256) void k_agg1(const float* __restrict__ h1,
                                              const float* __restrict__ dis,
                                              const int* __restrict__ rowptr,
                                              const int* __restrict__ cnt,
                                              const int* __restrict__ elist,
                                              float* __restrict__ agg1, int N) {
    int lane = threadIdx.x & 63;
    int i = blockIdx.x * 4 + (threadIdx.x >> 6);
    if (i >= N) return;
    const float2* h = (const float2*)h1;
    float accx = 0.f, accy = 0.f;
    int base = rowptr[i], c = cnt[i];
    for (int j = 0; j < c; ++j) {
        int s = elist[base + j];      // wave-uniform broadcast load
        float w = dis[s];             // wave-uniform broadcast load
        float2 v = h[s * 64 + lane];  // coalesced 512B row gather
        accx += w * v.x;
        accy += w * v.y;
    }
    float di = dis[i];
    float2 self = h[i * 64 + lane];
    float2 r;
    r.x = di * accx + di * di * self.x;
    r.y = di * accy + di * di * self.y;
    ((float2*)agg1)[i * 64 + lane] = r;
}

// ---------- BN stats (proven) ----------
__global__ __launch_bounds__(256) void k_bnstats(const float* __restrict__ agg1,
                                                 float* __restrict__ stats, int N) {
    int t = threadIdx.x;
    int f = t & 127, half = t >> 7;
    float s = 0.f, sq = 0.f;
    int stride = gridDim.x * 2;
    for (int r = blockIdx.x * 2 + half; r < N; r += stride) {
        float v = agg1[r * 128 + f];
        s += v; sq += v * v;
    }
    __shared__ float ls[256], lq[256];
    ls[t] = s; lq[t] = sq;
    __syncthreads();
    if (t < 128) {
        atomicAdd(&stats[f], ls[t] + ls[t + 128]);
        atomicAdd(&stats[128 + f], lq[t] + lq[t + 128]);
    }
}

// ---------- BN finalize (proven) ----------
__global__ void k_bnfin(float* __restrict__ stats, const float* __restrict__ gamma,
                        const float* __restrict__ beta, int N) {
    int f = threadIdx.x;
    if (f >= 128) return;
    float invN = 1.0f / (float)N;
    float mean = stats[f] * invN;
    float var = stats[128 + f] * invN - mean * mean;
    var = fmaxf(var, 0.f);
    float inv = rsqrtf(var + 1e-5f);
    float sc = gamma[f] * inv;
    stats[256 + f] = sc;
    stats[384 + f] = beta[f] - mean * sc;
}

// ---------- GEMM2: proven naive structure, 4 outputs/thread ----------
// thread (n, q): h2[n][4q..4q+3] = relu(bn(agg1[n]))·{W2 rows 4q..4q+3}
__global__ __launch_bounds__(256) void k_gemm2(const float* __restrict__ agg1,
                                               const float* __restrict__ W2,
                                               const float* __restrict__ stats,
                                               float* __restrict__ h2, int NT) {
    int idx = blockIdx.x * 256 + threadIdx.x;
    if (idx >= NT) return;                 // NT = N*16
    int n = idx >> 4, q = idx & 15;
    const float4* ar = (const float4*)agg1 + n * 32;
    const float4* w0 = (const float4*)W2 + (q * 4) * 32;  // rows 4q..4q+3
    const float4* st = (const float4*)stats;
    float4 acc = make_float4(0.f, 0.f, 0.f, 0.f);
    for (int k = 0; k < 32; ++k) {
        float4 a = ar[k], sc = st[64 + k], sh = st[96 + k];
        float r0 = fmaxf(a.x * sc.x + sh.x, 0.f);
        float r1 = fmaxf(a.y * sc.y + sh.y, 0.f);
        float r2 = fmaxf(a.z * sc.z + sh.z, 0.f);
        float r3 = fmaxf(a.w * sc.w + sh.w, 0.f);
        float4 b0 = w0[k], b1 = w0[32 + k], b2 = w0[64 + k], b3 = w0[96 + k];
        acc.x += r0 * b0.x + r1 * b0.y + r2 * b0.z + r3 * b0.w;
        acc.y += r0 * b1.x + r1 * b1.y + r2 * b1.z + r3 * b1.w;
        acc.z += r0 * b2.x + r1 * b2.y + r2 * b2.z + r3 * b2.w;
        acc.w += r0 * b3.x + r1 * b3.y + r2 * b3.z + r3 * b3.w;
    }
    ((float4*)h2)[idx] = acc;
}

// ---------- layer-2 gather (structure = proven agg1), self-loop+b2 fused ----------
__global__ __launch_bounds__(256) void k_agg2(const float* __restrict__ h2,
                                              const float* __restrict__ dis,
                                              const int* __restrict__ rowptr,
                                              const int* __restrict__ cnt,
                                              const int* __restrict__ elist,
                                              const float* __restrict__ b2,
                                              float* __restrict__ out, int N) {
    int lane = threadIdx.x & 63;
    int i = blockIdx.x * 4 + (threadIdx.x >> 6);
    if (i >= N) return;
    float acc = 0.f;
    int base = rowptr[i], c = cnt[i];
    for (int j = 0; j < c; ++j) {
        int s = elist[base + j];      // wave-uniform broadcast load
        float w = dis[s];             // wave-uniform broadcast load
        acc += w * h2[s * 64 + lane]; // coalesced 256B row gather
    }
    float di = dis[i];
    out[i * 64 + lane] = di * acc + di * di * h2[i * 64 + lane] + b2[lane];
}

extern "C" void kernel_launch(void* const* d_in, const int* in_sizes, int n_in,
                              void* d_out, int out_size, void* d_ws, size_t ws_size,
                              hipStream_t stream) {
    const float* x     = (const float*)d_in[0];
    const void*  ei    = d_in[1];            // int64 or int32, probed on device
    const float* W1    = (const float*)d_in[2];
    // d_in[3] = b1: cancels exactly through BatchNorm -> skipped
    const float* gamma = (const float*)d_in[4];
    const float* beta  = (const float*)d_in[5];
    const float* W2    = (const float*)d_in[6];
    const float* b2    = (const float*)d_in[7];
    float* out = (float*)d_out;

    int N = in_sizes[0] / 128;
    int E = in_sizes[1] / 2;
    int NF = N * 128;

    // ---- workspace layout: identical to round 4 (110.4 MB, proven) ----
    int*   cnt    = (int*)d_ws;                          // N
    int*   rowptr = cnt + N;                             // N
    int*   rowcur = rowptr + N;                          // N
    int*   total4 = rowcur + N;                          // 4: [0]=alloc, [1]=flag
    float* stats  = (float*)(total4 + 4);                // 512
    float* dis    = stats + 512;                         // N
    int*   elist  = (int*)(dis + N);                     // E
    float* h1     = (float*)(elist + E);                 // N*128 f32 (16B-aligned)
    float* agg1   = h1 + (size_t)NF;                     // N*128 f32
    float* h2     = h1;                                  // overlay: h1 dead after agg1

    hipMemsetAsync(cnt, 0, (size_t)N * sizeof(int), stream);
    hipMemsetAsync(total4, 0, (4 + 512) * sizeof(int), stream);

    int* flag = total4 + 1;
    k_detect<<<1, 64, 0, stream>>>((const int*)ei, flag);

    int gE   = (E + 255) / 256;
    int gN   = (N + 255) / 256;
    int gG1  = (N * 32 + 255) / 256;
    int gG2  = (N * 16 + 255) / 256;
    int gAgg = (N + 3) / 4;

    k_count<<<gE, 256, 0, stream>>>(ei, cnt, flag, E, N);
    k_disalloc<<<gN, 256, 0, stream>>>(cnt, dis, rowptr, rowcur, total4, N);
    k_fill<<<gE, 256, 0, stream>>>(ei, rowcur, elist, flag, E, N);
    k_gemm1<<<gG1, 256, 0, stream>>>(x, W1, h1, N * 32);
    k_agg1<<<gAgg, 256, 0, stream>>>(h1, dis, rowptr, cnt, elist, agg1, N);
    k_bnstats<<<500, 256, 0, stream>>>(agg1, stats, N);
    k_bnfin<<<1, 128, 0, stream>>>(stats, gamma, beta, N);
    k_gemm2<<<gG2, 256, 0, stream>>>(agg1, W2, stats, h2, N * 16);
    k_agg2<<<gAgg, 256, 0, stream>>>(h2, dis, rowptr, cnt, elist, b2, out, N);
}

// Round 7
// 864.074 us; speedup vs baseline: 6.9187x; 2.1056x over previous
//
#include <hip/hip_runtime.h>

// GCNEncoder — round 7: R6-passing kernel + transposed-weight GEMMs.
//   Weights pre-transposed to WT[k][o] in ws -> W loads are coalesced
//   (contiguous across q-lanes) instead of a 64-line gather per instr.
//   GEMMs: 4 nodes x 4 outputs per thread, no LDS, no barriers.
//   Aggregations: CSR + wave-per-node gather (proven R4/R6).
// b1 cancels exactly through BatchNorm -> skipped.

__device__ __forceinline__ void fma4(float4& acc, float s, const float4& w) {
    acc.x += s * w.x; acc.y += s * w.y; acc.z += s * w.z; acc.w += s * w.w;
}

// ---------- dtype probe: edge_index may be int64 or int32 ----------
__global__ void k_detect(const int* __restrict__ ei32, int* __restrict__ flag) {
    if (threadIdx.x == 0 && blockIdx.x == 0) {
        int o = 0;
        for (int q = 0; q < 16; ++q) o |= ei32[2 * q + 1];
        flag[0] = (o == 0) ? 1 : 0;  // 1 => int64 (high dwords all zero)
    }
}

// ---------- degree count (real edges at dst) ----------
__global__ __launch_bounds__(256) void k_count(const void* __restrict__ eiv,
                                               int* __restrict__ cnt,
                                               const int* __restrict__ flag,
                                               int E, int N) {
    int e = blockIdx.x * 256 + threadIdx.x;
    if (e >= E) return;
    int d;
    if (flag[0]) d = (int)((const long long*)eiv)[E + e];
    else         d = ((const int*)eiv)[E + e];
    if ((unsigned)d < (unsigned)N) atomicAdd(&cnt[d], 1);
}

// ---------- dis = rsqrt(deg+1); CSR region alloc via plain atomicAdd ----------
__global__ __launch_bounds__(256) void k_disalloc(const int* __restrict__ cnt,
                                                  float* __restrict__ dis,
                                                  int* __restrict__ rowptr,
                                                  int* __restrict__ rowcur,
                                                  int* __restrict__ total, int N) {
    int i = blockIdx.x * 256 + threadIdx.x;
    if (i >= N) return;
    int c = cnt[i];
    dis[i] = rsqrtf((float)c + 1.0f);
    int pos = atomicAdd(total, c);   // region order arbitrary; that's fine
    rowptr[i] = pos;
    rowcur[i] = pos;
}

// ---------- CSR fill ----------
__global__ __launch_bounds__(256) void k_fill(const void* __restrict__ eiv,
                                              int* __restrict__ rowcur,
                                              int* __restrict__ elist,
                                              const int* __restrict__ flag,
                                              int E, int N) {
    int e = blockIdx.x * 256 + threadIdx.x;
    if (e >= E) return;
    int s, d;
    if (flag[0]) {
        s = (int)((const long long*)eiv)[e];
        d = (int)((const long long*)eiv)[E + e];
    } else {
        s = ((const int*)eiv)[e];
        d = ((const int*)eiv)[E + e];
    }
    if ((unsigned)s >= (unsigned)N || (unsigned)d >= (unsigned)N) return;
    int p = atomicAdd(&rowcur[d], 1);
    elist[p] = s;
}

// ---------- weight transpose: dst[k][o] = src[o][k], K=128 ----------
__global__ __launch_bounds__(256) void k_transpose(const float* __restrict__ src,
                                                   float* __restrict__ dst, int O) {
    int idx = blockIdx.x * 256 + threadIdx.x;
    if (idx >= O * 128) return;
    int k = idx & 127, o = idx >> 7;
    dst[k * O + o] = src[o * 128 + k];
}

// ---------- GEMM1: h1[n][o] = x[n]·W1[o], W as WT1[k][o] ----------
// block 256 = 8 node-groups x 32 output-quads; 4 nodes x 4 outputs / thread.
__global__ __launch_bounds__(256) void k_gemm1(const float* __restrict__ x,
                                               const float* __restrict__ WT1,
                                               float* __restrict__ h1, int N) {
    int t = threadIdx.x;
    int q = t & 31, g = t >> 5;
    int n0 = blockIdx.x * 32 + g * 4;
    const float4* xr0 = (const float4*)x + (size_t)min(n0 + 0, N - 1) * 32;
    const float4* xr1 = (const float4*)x + (size_t)min(n0 + 1, N - 1) * 32;
    const float4* xr2 = (const float4*)x + (size_t)min(n0 + 2, N - 1) * 32;
    const float4* xr3 = (const float4*)x + (size_t)min(n0 + 3, N - 1) * 32;
    const float4* wt = (const float4*)WT1;   // row k: 32 float4
    float4 acc0 = make_float4(0.f, 0.f, 0.f, 0.f), acc1 = acc0, acc2 = acc0, acc3 = acc0;
    for (int kq = 0; kq < 32; ++kq) {
        float4 a0 = xr0[kq], a1 = xr1[kq], a2 = xr2[kq], a3 = xr3[kq];
        float4 w0 = wt[(4 * kq + 0) * 32 + q];   // coalesced across q-lanes
        float4 w1 = wt[(4 * kq + 1) * 32 + q];
        float4 w2 = wt[(4 * kq + 2) * 32 + q];
        float4 w3 = wt[(4 * kq + 3) * 32 + q];
        fma4(acc0, a0.x, w0); fma4(acc0, a0.y, w1); fma4(acc0, a0.z, w2); fma4(acc0, a0.w, w3);
        fma4(acc1, a1.x, w0); fma4(acc1, a1.y, w1); fma4(acc1, a1.z, w2); fma4(acc1, a1.w, w3);
        fma4(acc2, a2.x, w0); fma4(acc2, a2.y, w1); fma4(acc2, a2.z, w2); fma4(acc2, a2.w, w3);
        fma4(acc3, a3.x, w0); fma4(acc3, a3.y, w1); fma4(acc3, a3.z, w2); fma4(acc3, a3.w, w3);
    }
    float4* h4 = (float4*)h1;
    if (n0 + 0 < N) h4[(size_t)(n0 + 0) * 32 + q] = acc0;
    if (n0 + 1 < N) h4[(size_t)(n0 + 1) * 32 + q] = acc1;
    if (n0 + 2 < N) h4[(size_t)(n0 + 2) * 32 + q] = acc2;
    if (n0 + 3 < N) h4[(size_t)(n0 + 3) * 32 + q] = acc3;
}

// ---------- layer-1 gather (proven) ----------
__global__ __launch_bounds__(256) void k_agg1(const float* __restrict__ h1,
                                              const float* __restrict__ dis,
                                              const int* __restrict__ rowptr,
                                              const int* __restrict__ cnt,
                                              const int* __restrict__ elist,
                                              float* __restrict__ agg1, int N) {
    int lane = threadIdx.x & 63;
    int i = blockIdx.x * 4 + (threadIdx.x >> 6);
    if (i >= N) return;
    const float2* h = (const float2*)h1;
    float accx = 0.f, accy = 0.f;
    int base = rowptr[i], c = cnt[i];
    for (int j = 0; j < c; ++j) {
        int s = elist[base + j];      // wave-uniform broadcast load
        float w = dis[s];             // wave-uniform broadcast load
        float2 v = h[s * 64 + lane];  // coalesced 512B row gather
        accx += w * v.x;
        accy += w * v.y;
    }
    float di = dis[i];
    float2 self = h[i * 64 + lane];
    float2 r;
    r.x = di * accx + di * di * self.x;
    r.y = di * accy + di * di * self.y;
    ((float2*)agg1)[i * 64 + lane] = r;
}

// ---------- BN stats (proven) ----------
__global__ __launch_bounds__(256) void k_bnstats(const float* __restrict__ agg1,
                                                 float* __restrict__ stats, int N) {
    int t = threadIdx.x;
    int f = t & 127, half = t >> 7;
    float s = 0.f, sq = 0.f;
    int stride = gridDim.x * 2;
    for (int r = blockIdx.x * 2 + half; r < N; r += stride) {
        float v = agg1[r * 128 + f];
        s += v; sq += v * v;
    }
    __shared__ float ls[256], lq[256];
    ls[t] = s; lq[t] = sq;
    __syncthreads();
    if (t < 128) {
        atomicAdd(&stats[f], ls[t] + ls[t + 128]);
        atomicAdd(&stats[128 + f], lq[t] + lq[t + 128]);
    }
}

// ---------- BN finalize (proven) ----------
__global__ void k_bnfin(float* __restrict__ stats, const float* __restrict__ gamma,
                        const float* __restrict__ beta, int N) {
    int f = threadIdx.x;
    if (f >= 128) return;
    float invN = 1.0f / (float)N;
    float mean = stats[f] * invN;
    float var = stats[128 + f] * invN - mean * mean;
    var = fmaxf(var, 0.f);
    float inv = rsqrtf(var + 1e-5f);
    float sc = gamma[f] * inv;
    stats[256 + f] = sc;
    stats[384 + f] = beta[f] - mean * sc;
}

// ---------- GEMM2: h2[n][o] = relu(bn(agg1[n]))·W2[o], W as WT2[k][o] ----------
// block 256 = 16 node-groups x 16 output-quads; 4 nodes x 4 outputs / thread.
__global__ __launch_bounds__(256) void k_gemm2(const float* __restrict__ agg1,
                                               const float* __restrict__ WT2,
                                               const float* __restrict__ stats,
                                               float* __restrict__ h2, int N) {
    int t = threadIdx.x;
    int q = t & 15, g = t >> 4;
    int n0 = blockIdx.x * 64 + g * 4;
    const float4* ar0 = (const float4*)agg1 + (size_t)min(n0 + 0, N - 1) * 32;
    const float4* ar1 = (const float4*)agg1 + (size_t)min(n0 + 1, N - 1) * 32;
    const float4* ar2 = (const float4*)agg1 + (size_t)min(n0 + 2, N - 1) * 32;
    const float4* ar3 = (const float4*)agg1 + (size_t)min(n0 + 3, N - 1) * 32;
    const float4* wt = (const float4*)WT2;   // row k: 16 float4
    const float4* st = (const float4*)stats;
    float4 acc0 = make_float4(0.f, 0.f, 0.f, 0.f), acc1 = acc0, acc2 = acc0, acc3 = acc0;
    for (int kq = 0; kq < 32; ++kq) {
        float4 sc = st[64 + kq], sh = st[96 + kq];
        float4 a0 = ar0[kq], a1 = ar1[kq], a2 = ar2[kq], a3 = ar3[kq];
        float4 r0, r1, r2, r3;
        r0.x = fmaxf(a0.x * sc.x + sh.x, 0.f); r0.y = fmaxf(a0.y * sc.y + sh.y, 0.f);
        r0.z = fmaxf(a0.z * sc.z + sh.z, 0.f); r0.w = fmaxf(a0.w * sc.w + sh.w, 0.f);
        r1.x = fmaxf(a1.x * sc.x + sh.x, 0.f); r1.y = fmaxf(a1.y * sc.y + sh.y, 0.f);
        r1.z = fmaxf(a1.z * sc.z + sh.z, 0.f); r1.w = fmaxf(a1.w * sc.w + sh.w, 0.f);
        r2.x = fmaxf(a2.x * sc.x + sh.x, 0.f); r2.y = fmaxf(a2.y * sc.y + sh.y, 0.f);
        r2.z = fmaxf(a2.z * sc.z + sh.z, 0.f); r2.w = fmaxf(a2.w * sc.w + sh.w, 0.f);
        r3.x = fmaxf(a3.x * sc.x + sh.x, 0.f); r3.y = fmaxf(a3.y * sc.y + sh.y, 0.f);
        r3.z = fmaxf(a3.z * sc.z + sh.z, 0.f); r3.w = fmaxf(a3.w * sc.w + sh.w, 0.f);
        float4 w0 = wt[(4 * kq + 0) * 16 + q];   // coalesced across q-lanes
        float4 w1 = wt[(4 * kq + 1) * 16 + q];
        float4 w2 = wt[(4 * kq + 2) * 16 + q];
        float4 w3 = wt[(4 * kq + 3) * 16 + q];
        fma4(acc0, r0.x, w0); fma4(acc0, r0.y, w1); fma4(acc0, r0.z, w2); fma4(acc0, r0.w, w3);
        fma4(acc1, r1.x, w0); fma4(acc1, r1.y, w1); fma4(acc1, r1.z, w2); fma4(acc1, r1.w, w3);
        fma4(acc2, r2.x, w0); fma4(acc2, r2.y, w1); fma4(acc2, r2.z, w2); fma4(acc2, r2.w, w3);
        fma4(acc3, r3.x, w0); fma4(acc3, r3.y, w1); fma4(acc3, r3.z, w2); fma4(acc3, r3.w, w3);
    }
    float4* h4 = (float4*)h2;
    if (n0 + 0 < N) h4[(size_t)(n0 + 0) * 16 + q] = acc0;
    if (n0 + 1 < N) h4[(size_t)(n0 + 1) * 16 + q] = acc1;
    if (n0 + 2 < N) h4[(size_t)(n0 + 2) * 16 + q] = acc2;
    if (n0 + 3 < N) h4[(size_t)(n0 + 3) * 16 + q] = acc3;
}

// ---------- layer-2 gather (proven), self-loop+b2 fused ----------
__global__ __launch_bounds__(256) void k_agg2(const float* __restrict__ h2,
                                              const float* __restrict__ dis,
                                              const int* __restrict__ rowptr,
                                              const int* __restrict__ cnt,
                                              const int* __restrict__ elist,
                                              const float* __restrict__ b2,
                                              float* __restrict__ out, int N) {
    int lane = threadIdx.x & 63;
    int i = blockIdx.x * 4 + (threadIdx.x >> 6);
    if (i >= N) return;
    float acc = 0.f;
    int base = rowptr[i], c = cnt[i];
    for (int j = 0; j < c; ++j) {
        int s = elist[base + j];      // wave-uniform broadcast load
        float w = dis[s];             // wave-uniform broadcast load
        acc += w * h2[s * 64 + lane]; // coalesced 256B row gather
    }
    float di = dis[i];
    out[i * 64 + lane] = di * acc + di * di * h2[i * 64 + lane] + b2[lane];
}

extern "C" void kernel_launch(void* const* d_in, const int* in_sizes, int n_in,
                              void* d_out, int out_size, void* d_ws, size_t ws_size,
                              hipStream_t stream) {
    const float* x     = (const float*)d_in[0];
    const void*  ei    = d_in[1];            // int64 or int32, probed on device
    const float* W1    = (const float*)d_in[2];
    // d_in[3] = b1: cancels exactly through BatchNorm -> skipped
    const float* gamma = (const float*)d_in[4];
    const float* beta  = (const float*)d_in[5];
    const float* W2    = (const float*)d_in[6];
    const float* b2    = (const float*)d_in[7];
    float* out = (float*)d_out;

    int N = in_sizes[0] / 128;
    int E = in_sizes[1] / 2;
    int NF = N * 128;

    // ---- workspace layout: R4/R6-proven + WT1/WT2 appended (~110.5 MB) ----
    int*   cnt    = (int*)d_ws;                          // N
    int*   rowptr = cnt + N;                             // N
    int*   rowcur = rowptr + N;                          // N
    int*   total4 = rowcur + N;                          // 4: [0]=alloc, [1]=flag
    float* stats  = (float*)(total4 + 4);                // 512
    float* dis    = stats + 512;                         // N
    int*   elist  = (int*)(dis + N);                     // E
    float* h1     = (float*)(elist + E);                 // N*128 f32 (16B-aligned)
    float* agg1   = h1 + (size_t)NF;                     // N*128 f32
    float* WT1    = agg1 + (size_t)NF;                   // 128*128
    float* WT2    = WT1 + 128 * 128;                     // 128*64
    float* h2     = h1;                                  // overlay: h1 dead after agg1

    hipMemsetAsync(cnt, 0, (size_t)N * sizeof(int), stream);
    hipMemsetAsync(total4, 0, (4 + 512) * sizeof(int), stream);

    int* flag = total4 + 1;
    k_detect<<<1, 64, 0, stream>>>((const int*)ei, flag);

    int gE   = (E + 255) / 256;
    int gN   = (N + 255) / 256;
    int gG1  = (N + 31) / 32;
    int gG2  = (N + 63) / 64;
    int gAgg = (N + 3) / 4;

    k_transpose<<<64, 256, 0, stream>>>(W1, WT1, 128);   // 16384 elems
    k_transpose<<<32, 256, 0, stream>>>(W2, WT2, 64);    // 8192 elems
    k_count<<<gE, 256, 0, stream>>>(ei, cnt, flag, E, N);
    k_disalloc<<<gN, 256, 0, stream>>>(cnt, dis, rowptr, rowcur, total4, N);
    k_fill<<<gE, 256, 0, stream>>>(ei, rowcur, elist, flag, E, N);
    k_gemm1<<<gG1, 256, 0, stream>>>(x, WT1, h1, N);
    k_agg1<<<gAgg, 256, 0, stream>>>(h1, dis, rowptr, cnt, elist, agg1, N);
    k_bnstats<<<500, 256, 0, stream>>>(agg1, stats, N);
    k_bnfin<<<1, 128, 0, stream>>>(stats, gamma, beta, N);
    k_gemm2<<<gG2, 256, 0, stream>>>(agg1, WT2, stats, h2, N);
    k_agg2<<<gAgg, 256, 0, stream>>>(h2, dis, rowptr, cnt, elist, b2, out, N);
}

// Round 8
// 752.729 us; speedup vs baseline: 7.9421x; 1.1479x over previous
//
#include <hip/hip_runtime.h>

// GCNEncoder — round 8: R7-passing kernel + 8-way batched prefetch in the
// CSR gathers (k_agg1/k_agg2). Independent loads per batch -> 8x MLP instead
// of one waitcnt-serialized dependent chain per edge. Accumulation order
// unchanged (bit-identical to R7).
// b1 cancels exactly through BatchNorm -> skipped.

__device__ __forceinline__ void fma4(float4& acc, float s, const float4& w) {
    acc.x += s * w.x; acc.y += s * w.y; acc.z += s * w.z; acc.w += s * w.w;
}

// ---------- dtype probe: edge_index may be int64 or int32 ----------
__global__ void k_detect(const int* __restrict__ ei32, int* __restrict__ flag) {
    if (threadIdx.x == 0 && blockIdx.x == 0) {
        int o = 0;
        for (int q = 0; q < 16; ++q) o |= ei32[2 * q + 1];
        flag[0] = (o == 0) ? 1 : 0;  // 1 => int64 (high dwords all zero)
    }
}

// ---------- degree count (real edges at dst) ----------
__global__ __launch_bounds__(256) void k_count(const void* __restrict__ eiv,
                                               int* __restrict__ cnt,
                                               const int* __restrict__ flag,
                                               int E, int N) {
    int e = blockIdx.x * 256 + threadIdx.x;
    if (e >= E) return;
    int d;
    if (flag[0]) d = (int)((const long long*)eiv)[E + e];
    else         d = ((const int*)eiv)[E + e];
    if ((unsigned)d < (unsigned)N) atomicAdd(&cnt[d], 1);
}

// ---------- dis = rsqrt(deg+1); CSR region alloc via plain atomicAdd ----------
__global__ __launch_bounds__(256) void k_disalloc(const int* __restrict__ cnt,
                                                  float* __restrict__ dis,
                                                  int* __restrict__ rowptr,
                                                  int* __restrict__ rowcur,
                                                  int* __restrict__ total, int N) {
    int i = blockIdx.x * 256 + threadIdx.x;
    if (i >= N) return;
    int c = cnt[i];
    dis[i] = rsqrtf((float)c + 1.0f);
    int pos = atomicAdd(total, c);   // region order arbitrary; that's fine
    rowptr[i] = pos;
    rowcur[i] = pos;
}

// ---------- CSR fill ----------
__global__ __launch_bounds__(256) void k_fill(const void* __restrict__ eiv,
                                              int* __restrict__ rowcur,
                                              int* __restrict__ elist,
                                              const int* __restrict__ flag,
                                              int E, int N) {
    int e = blockIdx.x * 256 + threadIdx.x;
    if (e >= E) return;
    int s, d;
    if (flag[0]) {
        s = (int)((const long long*)eiv)[e];
        d = (int)((const long long*)eiv)[E + e];
    } else {
        s = ((const int*)eiv)[e];
        d = ((const int*)eiv)[E + e];
    }
    if ((unsigned)s >= (unsigned)N || (unsigned)d >= (unsigned)N) return;
    int p = atomicAdd(&rowcur[d], 1);
    elist[p] = s;
}

// ---------- weight transpose: dst[k][o] = src[o][k], K=128 ----------
__global__ __launch_bounds__(256) void k_transpose(const float* __restrict__ src,
                                                   float* __restrict__ dst, int O) {
    int idx = blockIdx.x * 256 + threadIdx.x;
    if (idx >= O * 128) return;
    int k = idx & 127, o = idx >> 7;
    dst[k * O + o] = src[o * 128 + k];
}

// ---------- GEMM1: h1[n][o] = x[n]·W1[o], W as WT1[k][o] (R7 verbatim) ----------
__global__ __launch_bounds__(256) void k_gemm1(const float* __restrict__ x,
                                               const float* __restrict__ WT1,
                                               float* __restrict__ h1, int N) {
    int t = threadIdx.x;
    int q = t & 31, g = t >> 5;
    int n0 = blockIdx.x * 32 + g * 4;
    const float4* xr0 = (const float4*)x + (size_t)min(n0 + 0, N - 1) * 32;
    const float4* xr1 = (const float4*)x + (size_t)min(n0 + 1, N - 1) * 32;
    const float4* xr2 = (const float4*)x + (size_t)min(n0 + 2, N - 1) * 32;
    const float4* xr3 = (const float4*)x + (size_t)min(n0 + 3, N - 1) * 32;
    const float4* wt = (const float4*)WT1;   // row k: 32 float4
    float4 acc0 = make_float4(0.f, 0.f, 0.f, 0.f), acc1 = acc0, acc2 = acc0, acc3 = acc0;
    for (int kq = 0; kq < 32; ++kq) {
        float4 a0 = xr0[kq], a1 = xr1[kq], a2 = xr2[kq], a3 = xr3[kq];
        float4 w0 = wt[(4 * kq + 0) * 32 + q];   // coalesced across q-lanes
        float4 w1 = wt[(4 * kq + 1) * 32 + q];
        float4 w2 = wt[(4 * kq + 2) * 32 + q];
        float4 w3 = wt[(4 * kq + 3) * 32 + q];
        fma4(acc0, a0.x, w0); fma4(acc0, a0.y, w1); fma4(acc0, a0.z, w2); fma4(acc0, a0.w, w3);
        fma4(acc1, a1.x, w0); fma4(acc1, a1.y, w1); fma4(acc1, a1.z, w2); fma4(acc1, a1.w, w3);
        fma4(acc2, a2.x, w0); fma4(acc2, a2.y, w1); fma4(acc2, a2.z, w2); fma4(acc2, a2.w, w3);
        fma4(acc3, a3.x, w0); fma4(acc3, a3.y, w1); fma4(acc3, a3.z, w2); fma4(acc3, a3.w, w3);
    }
    float4* h4 = (float4*)h1;
    if (n0 + 0 < N) h4[(size_t)(n0 + 0) * 32 + q] = acc0;
    if (n0 + 1 < N) h4[(size_t)(n0 + 1) * 32 + q] = acc1;
    if (n0 + 2 < N) h4[(size_t)(n0 + 2) * 32 + q] = acc2;
    if (n0 + 3 < N) h4[(size_t)(n0 + 3) * 32 + q] = acc3;
}

// ---------- layer-1 gather: 8-way batched prefetch, same accumulation order ----------
__global__ __launch_bounds__(256) void k_agg1(const float* __restrict__ h1,
                                              const float* __restrict__ dis,
                                              const int* __restrict__ rowptr,
                                              const int* __restrict__ cnt,
                                              const int* __restrict__ elist,
                                              float* __restrict__ agg1, int N) {
    int lane = threadIdx.x & 63;
    int i = blockIdx.x * 4 + (threadIdx.x >> 6);
    if (i >= N) return;
    const float2* h = (const float2*)h1;
    float accx = 0.f, accy = 0.f;
    int base = rowptr[i], c = cnt[i];
    int j = 0;
    for (; j + 8 <= c; j += 8) {
        int ss[8];
#pragma unroll
        for (int r = 0; r < 8; ++r) ss[r] = elist[base + j + r];   // independent
        float ww[8];
#pragma unroll
        for (int r = 0; r < 8; ++r) ww[r] = dis[ss[r]];            // independent
        float2 vv[8];
#pragma unroll
        for (int r = 0; r < 8; ++r) vv[r] = h[(size_t)ss[r] * 64 + lane];  // independent
#pragma unroll
        for (int r = 0; r < 8; ++r) { accx += ww[r] * vv[r].x; accy += ww[r] * vv[r].y; }
    }
    for (; j < c; ++j) {
        int s = elist[base + j];
        float w = dis[s];
        float2 v = h[(size_t)s * 64 + lane];
        accx += w * v.x;
        accy += w * v.y;
    }
    float di = dis[i];
    float2 self = h[(size_t)i * 64 + lane];
    float2 r;
    r.x = di * accx + di * di * self.x;
    r.y = di * accy + di * di * self.y;
    ((float2*)agg1)[(size_t)i * 64 + lane] = r;
}

// ---------- BN stats (proven) ----------
__global__ __launch_bounds__(256) void k_bnstats(const float* __restrict__ agg1,
                                                 float* __restrict__ stats, int N) {
    int t = threadIdx.x;
    int f = t & 127, half = t >> 7;
    float s = 0.f, sq = 0.f;
    int stride = gridDim.x * 2;
    for (int r = blockIdx.x * 2 + half; r < N; r += stride) {
        float v = agg1[r * 128 + f];
        s += v; sq += v * v;
    }
    __shared__ float ls[256], lq[256];
    ls[t] = s; lq[t] = sq;
    __syncthreads();
    if (t < 128) {
        atomicAdd(&stats[f], ls[t] + ls[t + 128]);
        atomicAdd(&stats[128 + f], lq[t] + lq[t + 128]);
    }
}

// ---------- BN finalize (proven) ----------
__global__ void k_bnfin(float* __restrict__ stats, const float* __restrict__ gamma,
                        const float* __restrict__ beta, int N) {
    int f = threadIdx.x;
    if (f >= 128) return;
    float invN = 1.0f / (float)N;
    float mean = stats[f] * invN;
    float var = stats[128 + f] * invN - mean * mean;
    var = fmaxf(var, 0.f);
    float inv = rsqrtf(var + 1e-5f);
    float sc = gamma[f] * inv;
    stats[256 + f] = sc;
    stats[384 + f] = beta[f] - mean * sc;
}

// ---------- GEMM2 (R7 verbatim): h2[n][o] = relu(bn(agg1[n]))·W2[o] ----------
__global__ __launch_bounds__(256) void k_gemm2(const float* __restrict__ agg1,
                                               const float* __restrict__ WT2,
                                               const float* __restrict__ stats,
                                               float* __restrict__ h2, int N) {
    int t = threadIdx.x;
    int q = t & 15, g = t >> 4;
    int n0 = blockIdx.x * 64 + g * 4;
    const float4* ar0 = (const float4*)agg1 + (size_t)min(n0 + 0, N - 1) * 32;
    const float4* ar1 = (const float4*)agg1 + (size_t)min(n0 + 1, N - 1) * 32;
    const float4* ar2 = (const float4*)agg1 + (size_t)min(n0 + 2, N - 1) * 32;
    const float4* ar3 = (const float4*)agg1 + (size_t)min(n0 + 3, N - 1) * 32;
    const float4* wt = (const float4*)WT2;   // row k: 16 float4
    const float4* st = (const float4*)stats;
    float4 acc0 = make_float4(0.f, 0.f, 0.f, 0.f), acc1 = acc0, acc2 = acc0, acc3 = acc0;
    for (int kq = 0; kq < 32; ++kq) {
        float4 sc = st[64 + kq], sh = st[96 + kq];
        float4 a0 = ar0[kq], a1 = ar1[kq], a2 = ar2[kq], a3 = ar3[kq];
        float4 r0, r1, r2, r3;
        r0.x = fmaxf(a0.x * sc.x + sh.x, 0.f); r0.y = fmaxf(a0.y * sc.y + sh.y, 0.f);
        r0.z = fmaxf(a0.z * sc.z + sh.z, 0.f); r0.w = fmaxf(a0.w * sc.w + sh.w, 0.f);
        r1.x = fmaxf(a1.x * sc.x + sh.x, 0.f); r1.y = fmaxf(a1.y * sc.y + sh.y, 0.f);
        r1.z = fmaxf(a1.z * sc.z + sh.z, 0.f); r1.w = fmaxf(a1.w * sc.w + sh.w, 0.f);
        r2.x = fmaxf(a2.x * sc.x + sh.x, 0.f); r2.y = fmaxf(a2.y * sc.y + sh.y, 0.f);
        r2.z = fmaxf(a2.z * sc.z + sh.z, 0.f); r2.w = fmaxf(a2.w * sc.w + sh.w, 0.f);
        r3.x = fmaxf(a3.x * sc.x + sh.x, 0.f); r3.y = fmaxf(a3.y * sc.y + sh.y, 0.f);
        r3.z = fmaxf(a3.z * sc.z + sh.z, 0.f); r3.w = fmaxf(a3.w * sc.w + sh.w, 0.f);
        float4 w0 = wt[(4 * kq + 0) * 16 + q];   // coalesced across q-lanes
        float4 w1 = wt[(4 * kq + 1) * 16 + q];
        float4 w2 = wt[(4 * kq + 2) * 16 + q];
        float4 w3 = wt[(4 * kq + 3) * 16 + q];
        fma4(acc0, r0.x, w0); fma4(acc0, r0.y, w1); fma4(acc0, r0.z, w2); fma4(acc0, r0.w, w3);
        fma4(acc1, r1.x, w0); fma4(acc1, r1.y, w1); fma4(acc1, r1.z, w2); fma4(acc1, r1.w, w3);
        fma4(acc2, r2.x, w0); fma4(acc2, r2.y, w1); fma4(acc2, r2.z, w2); fma4(acc2, r2.w, w3);
        fma4(acc3, r3.x, w0); fma4(acc3, r3.y, w1); fma4(acc3, r3.z, w2); fma4(acc3, r3.w, w3);
    }
    float4* h4 = (float4*)h2;
    if (n0 + 0 < N) h4[(size_t)(n0 + 0) * 16 + q] = acc0;
    if (n0 + 1 < N) h4[(size_t)(n0 + 1) * 16 + q] = acc1;
    if (n0 + 2 < N) h4[(size_t)(n0 + 2) * 16 + q] = acc2;
    if (n0 + 3 < N) h4[(size_t)(n0 + 3) * 16 + q] = acc3;
}

// ---------- layer-2 gather: 8-way batched prefetch, self-loop+b2 fused ----------
__global__ __launch_bounds__(256) void k_agg2(const float* __restrict__ h2,
                                              const float* __restrict__ dis,
                                              const int* __restrict__ rowptr,
                                              const int* __restrict__ cnt,
                                              const int* __restrict__ elist,
                                              const float* __restrict__ b2,
                                              float* __restrict__ out, int N) {
    int lane = threadIdx.x & 63;
    int i = blockIdx.x * 4 + (threadIdx.x >> 6);
    if (i >= N) return;
    float acc = 0.f;
    int base = rowptr[i], c = cnt[i];
    int j = 0;
    for (; j + 8 <= c; j += 8) {
        int ss[8];
#pragma unroll
        for (int r = 0; r < 8; ++r) ss[r] = elist[base + j + r];   // independent
        float ww[8];
#pragma unroll
        for (int r = 0; r < 8; ++r) ww[r] = dis[ss[r]];            // independent
        float vv[8];
#pragma unroll
        for (int r = 0; r < 8; ++r) vv[r] = h2[(size_t)ss[r] * 64 + lane];  // independent
#pragma unroll
        for (int r = 0; r < 8; ++r) acc += ww[r] * vv[r];
    }
    for (; j < c; ++j) {
        int s = elist[base + j];
        float w = dis[s];
        acc += w * h2[(size_t)s * 64 + lane];
    }
    float di = dis[i];
    out[(size_t)i * 64 + lane] = di * acc + di * di * h2[(size_t)i * 64 + lane] + b2[lane];
}

extern "C" void kernel_launch(void* const* d_in, const int* in_sizes, int n_in,
                              void* d_out, int out_size, void* d_ws, size_t ws_size,
                              hipStream_t stream) {
    const float* x     = (const float*)d_in[0];
    const void*  ei    = d_in[1];            // int64 or int32, probed on device
    const float* W1    = (const float*)d_in[2];
    // d_in[3] = b1: cancels exactly through BatchNorm -> skipped
    const float* gamma = (const float*)d_in[4];
    const float* beta  = (const float*)d_in[5];
    const float* W2    = (const float*)d_in[6];
    const float* b2    = (const float*)d_in[7];
    float* out = (float*)d_out;

    int N = in_sizes[0] / 128;
    int E = in_sizes[1] / 2;
    int NF = N * 128;

    // ---- workspace layout: R7-proven (~110.5 MB) ----
    int*   cnt    = (int*)d_ws;                          // N
    int*   rowptr = cnt + N;                             // N
    int*   rowcur = rowptr + N;                          // N
    int*   total4 = rowcur + N;                          // 4: [0]=alloc, [1]=flag
    float* stats  = (float*)(total4 + 4);                // 512
    float* dis    = stats + 512;                         // N
    int*   elist  = (int*)(dis + N);                     // E
    float* h1     = (float*)(elist + E);                 // N*128 f32 (16B-aligned)
    float* agg1   = h1 + (size_t)NF;                     // N*128 f32
    float* WT1    = agg1 + (size_t)NF;                   // 128*128
    float* WT2    = WT1 + 128 * 128;                     // 128*64
    float* h2     = h1;                                  // overlay: h1 dead after agg1

    hipMemsetAsync(cnt, 0, (size_t)N * sizeof(int), stream);
    hipMemsetAsync(total4, 0, (4 + 512) * sizeof(int), stream);

    int* flag = total4 + 1;
    k_detect<<<1, 64, 0, stream>>>((const int*)ei, flag);

    int gE   = (E + 255) / 256;
    int gN   = (N + 255) / 256;
    int gG1  = (N + 31) / 32;
    int gG2  = (N + 63) / 64;
    int gAgg = (N + 3) / 4;

    k_transpose<<<64, 256, 0, stream>>>(W1, WT1, 128);   // 16384 elems
    k_transpose<<<32, 256, 0, stream>>>(W2, WT2, 64);    // 8192 elems
    k_count<<<gE, 256, 0, stream>>>(ei, cnt, flag, E, N);
    k_disalloc<<<gN, 256, 0, stream>>>(cnt, dis, rowptr, rowcur, total4, N);
    k_fill<<<gE, 256, 0, stream>>>(ei, rowcur, elist, flag, E, N);
    k_gemm1<<<gG1, 256, 0, stream>>>(x, WT1, h1, N);
    k_agg1<<<gAgg, 256, 0, stream>>>(h1, dis, rowptr, cnt, elist, agg1, N);
    k_bnstats<<<500, 256, 0, stream>>>(agg1, stats, N);
    k_bnfin<<<1, 128, 0, stream>>>(stats, gamma, beta, N);
    k_gemm2<<<gG2, 256, 0, stream>>>(agg1, WT2, stats, h2, N);
    k_agg2<<<gAgg, 256, 0, stream>>>(h2, dis, rowptr, cnt, elist, b2, out, N);
}